// Round 2
// baseline (745.508 us; speedup 1.0000x reference)
//
#include <hip/hip_runtime.h>
#include <stdint.h>

typedef __attribute__((ext_vector_type(8))) __bf16 bf16x8;
typedef __attribute__((ext_vector_type(4))) float f32x4;
typedef __attribute__((ext_vector_type(4))) int i32x4;

#define DEVI static __device__ __forceinline__

constexpr int NN = 2048;   // sequence length
constexpr int DD = 64;     // head dim
constexpr int NH = 16;     // heads
constexpr int NG = 8;      // global heads
constexpr float SCALE = 0.125f;         // 1/sqrt(64)
constexpr float NEGBIG = -1.0e12f;      // MAX_VAL in reference
constexpr size_t OUT_ELEMS = (size_t)2 * NH * NN * DD;      // 4194304
constexpr size_t PG_ELEMS  = (size_t)2 * NG * NN * NN;      // 67108864

struct Frag { bf16x8 hi, lo; };

// fp32 -> (bf16 hi, bf16 lo) split fragment from 8 contiguous floats
DEVI Frag make_frag(const float* p) {
  f32x4 a = *(const f32x4*)p;
  f32x4 b = *(const f32x4*)(p + 4);
  Frag f;
#pragma unroll
  for (int j = 0; j < 8; j++) {
    float x = (j < 4) ? a[j] : b[j - 4];
    __bf16 h = (__bf16)x;
    f.hi[j] = h;
    f.lo[j] = (__bf16)(x - (float)h);
  }
  return f;
}

DEVI f32x4 mfma(bf16x8 a, bf16x8 b, f32x4 c) {
  return __builtin_amdgcn_mfma_f32_16x16x32_bf16(a, b, c, 0, 0, 0);
}

// S^T tile for one (rs): acc[Mt][r] = S[row = rb+rs*16+li][col = wc+Mt*16+4*qi+r]
// computed as K · Q^T with hi/lo split (drop lo*lo term).
DEVI void compute_st(const Frag kf[2][2], const Frag* qf_rs, f32x4 acc[2]) {
#pragma unroll
  for (int Mt = 0; Mt < 2; Mt++) {
    f32x4 c = {0.f, 0.f, 0.f, 0.f};
#pragma unroll
    for (int ks = 0; ks < 2; ks++) {
      c = mfma(kf[Mt][ks].hi, qf_rs[ks].hi, c);
      c = mfma(kf[Mt][ks].hi, qf_rs[ks].lo, c);
      c = mfma(kf[Mt][ks].lo, qf_rs[ks].hi, c);
    }
    acc[Mt] = c;
  }
}

__global__ __launch_bounds__(256, 2)
void wattn(const float* __restrict__ Q, const float* __restrict__ K,
           const float* __restrict__ V, const int* __restrict__ MSK,
           float* __restrict__ OUT) {
  const int bid = blockIdx.x;
  const bool loc = bid >= 256;
  const int lb = loc ? bid - 256 : bid;
  const int bh = lb >> 4;           // 0..15 -> (b, head-within-group)
  const int b  = bh >> 3;
  const int hh = bh & 7;
  const int h  = loc ? (hh + 8) : hh;
  const int wave = (int)(threadIdx.x >> 6);
  const int lane = (int)(threadIdx.x & 63);
  const int qi = lane >> 4;         // quad
  const int li = lane & 15;
  const int rb = (lb & 15) * 128 + wave * 32;  // 32-row strip per wave

  const float* qp = Q + ((size_t)(b * NH + h) * NN) * DD;
  const float* kp = K + ((size_t)(b * NH + h) * NN) * DD;
  const float* vp = V + ((size_t)(b * NH + h) * NN) * DD;
  const int*   mp = MSK + (size_t)b * NN;
  float* op = OUT + ((size_t)(b * NH + h) * NN) * DD;
  float* pp = OUT + OUT_ELEMS + (loc ? PG_ELEMS : (size_t)0)
                  + ((size_t)(b * NG + hh) * NN) * NN;

  // Q fragments (B-operand of S^T mfma): rows rb + rs*16 + li, 8 consecutive d
  Frag qf[2][2];
#pragma unroll
  for (int rs = 0; rs < 2; rs++)
#pragma unroll
    for (int ks = 0; ks < 2; ks++)
      qf[rs][ks] = make_frag(qp + (size_t)(rb + rs * 16 + li) * DD + ks * 32 + qi * 8);

  // local heads: zero-fill p rows outside the band window [wlo, whi)
  int wlo = 0, whi = 0;
  if (loc) {
    wlo = rb - 64; if (wlo < 0) wlo = 0;
    whi = rb + 96; if (whi > NN) whi = NN;
    const f32x4 z = {0.f, 0.f, 0.f, 0.f};
#pragma unroll 1
    for (int rr = 0; rr < 32; rr++) {
      float* dst = pp + (size_t)(rb + rr) * NN;
#pragma unroll 1
      for (int c = lane * 4; c < NN; c += 256) {
        if (c >= wlo && c < whi) continue;
        *(f32x4*)(dst + c) = z;
      }
    }
  }

  const int ntiles = loc ? 5 : 64;

  float m[2] = {NEGBIG, NEGBIG};
  float l[2] = {0.f, 0.f};

  // ---------------- Sweep A: online row max + sum ----------------
#pragma unroll 1
  for (int t = 0; t < ntiles; t++) {
    const int wc = loc ? (rb - 64 + 32 * t) : (32 * t);
    if (wc < 0 || wc >= NN) continue;

    Frag kf[2][2];
#pragma unroll
    for (int Mt = 0; Mt < 2; Mt++)
#pragma unroll
      for (int ks = 0; ks < 2; ks++)
        kf[Mt][ks] = make_frag(kp + (size_t)(wc + Mt * 16 + li) * DD + ks * 32 + qi * 8);

    i32x4 mv[2];
    mv[0] = *(const i32x4*)(mp + wc + qi * 4);
    mv[1] = *(const i32x4*)(mp + wc + 16 + qi * 4);

#pragma unroll
    for (int rs = 0; rs < 2; rs++) {
      f32x4 acc[2];
      compute_st(kf, qf[rs], acc);
      const int row = rb + rs * 16 + li;
      float vals[8];
#pragma unroll
      for (int Mt = 0; Mt < 2; Mt++)
#pragma unroll
        for (int r = 0; r < 4; r++) {
          const int col = wc + Mt * 16 + qi * 4 + r;
          bool ok = (mv[Mt][r] != 0);
          if (loc) { int d = row - col; if (d < 0) d = -d; ok = ok && (d <= 64); }
          vals[Mt * 4 + r] = ok ? acc[Mt][r] * SCALE : NEGBIG;
        }
      float mx = vals[0];
#pragma unroll
      for (int j = 1; j < 8; j++) mx = fmaxf(mx, vals[j]);
      const float mn = fmaxf(m[rs], mx);
      float s = 0.f;
#pragma unroll
      for (int j = 0; j < 8; j++) s += __expf(vals[j] - mn);
      l[rs] = l[rs] * __expf(m[rs] - mn) + s;
      m[rs] = mn;
    }
  }

  // combine partial (m,l) across the 4 quads (lanes differing in bits 4,5)
  float rl[2];
#pragma unroll
  for (int rs = 0; rs < 2; rs++) {
#pragma unroll
    for (int off = 16; off <= 32; off <<= 1) {
      const float mo = __shfl_xor(m[rs], off);
      const float lo2 = __shfl_xor(l[rs], off);
      const float mn = fmaxf(m[rs], mo);
      l[rs] = l[rs] * __expf(m[rs] - mn) + lo2 * __expf(mo - mn);
      m[rs] = mn;
    }
    rl[rs] = 1.0f / l[rs];
  }

  // ---------------- Sweep B: P = softmax, store P, O += P·V ----------------
  f32x4 o[2][4];
#pragma unroll
  for (int rs = 0; rs < 2; rs++)
#pragma unroll
    for (int dt = 0; dt < 4; dt++) o[rs][dt] = (f32x4){0.f, 0.f, 0.f, 0.f};

  // shuffle sources: C-layout -> A-layout. target lane (qi,li), col cc=8*qi+j:
  // src quad q' = (2*qi + (j>>2)) & 3, src lane = q'*16 + li, Mt = qi>>1, reg = j&3
  const int srcA = (((qi * 2) + 0) & 3) * 16 + li;
  const int srcB = (((qi * 2) + 1) & 3) * 16 + li;
  const bool selB = (qi >> 1) != 0;

#pragma unroll 1
  for (int t = 0; t < ntiles; t++) {
    const int wc = loc ? (rb - 64 + 32 * t) : (32 * t);
    if (wc < 0 || wc >= NN) continue;

    Frag kf[2][2];
#pragma unroll
    for (int Mt = 0; Mt < 2; Mt++)
#pragma unroll
      for (int ks = 0; ks < 2; ks++)
        kf[Mt][ks] = make_frag(kp + (size_t)(wc + Mt * 16 + li) * DD + ks * 32 + qi * 8);

    i32x4 mv[2];
    mv[0] = *(const i32x4*)(mp + wc + qi * 4);
    mv[1] = *(const i32x4*)(mp + wc + 16 + qi * 4);

    // V fragments (B-operand of PV): vf[dt][j] = V[wc + 8*qi + j][dt*16 + li]
    bf16x8 vf[4];
#pragma unroll
    for (int dt = 0; dt < 4; dt++)
#pragma unroll
      for (int j = 0; j < 8; j++)
        vf[dt][j] = (__bf16)vp[(size_t)(wc + qi * 8 + j) * DD + dt * 16 + li];

#pragma unroll
    for (int rs = 0; rs < 2; rs++) {
      f32x4 acc[2];
      compute_st(kf, qf[rs], acc);
      const int row = rb + rs * 16 + li;
      float pf[8];
#pragma unroll
      for (int Mt = 0; Mt < 2; Mt++)
#pragma unroll
        for (int r = 0; r < 4; r++) {
          const int col = wc + Mt * 16 + qi * 4 + r;
          bool ok = (mv[Mt][r] != 0);
          if (loc) { int d = row - col; if (d < 0) d = -d; ok = ok && (d <= 64); }
          const float vv = ok ? acc[Mt][r] * SCALE : NEGBIG;
          pf[Mt * 4 + r] = __expf(vv - m[rs]) * rl[rs];
        }
      // C-layout -> A-layout via cross-quad shuffles
      float pa[8];
#pragma unroll
      for (int j = 0; j < 8; j++) {
        const int src = (j < 4) ? srcA : srcB;
        const float v0 = __shfl(pf[0 + (j & 3)], src);
        const float v1 = __shfl(pf[4 + (j & 3)], src);
        pa[j] = selB ? v1 : v0;
      }
      // coalesced P store (row-major, 8 consecutive cols per lane)
      float* prow = pp + (size_t)(rb + rs * 16 + li) * NN + wc + qi * 8;
      *(f32x4*)prow       = (f32x4){pa[0], pa[1], pa[2], pa[3]};
      *(f32x4*)(prow + 4) = (f32x4){pa[4], pa[5], pa[6], pa[7]};
      // PV accumulate (P already normalized)
      bf16x8 pb;
#pragma unroll
      for (int j = 0; j < 8; j++) pb[j] = (__bf16)pa[j];
#pragma unroll
      for (int dt = 0; dt < 4; dt++)
        o[rs][dt] = mfma(pb, vf[dt], o[rs][dt]);
    }
  }

  // epilogue: store O (C-layout: row = qi*4+r, col = li). P was already
  // normalized by 1/l before PV, so NO second normalization here.
#pragma unroll
  for (int rs = 0; rs < 2; rs++) {
#pragma unroll
    for (int dt = 0; dt < 4; dt++)
#pragma unroll
      for (int r = 0; r < 4; r++) {
        const int row = rb + rs * 16 + qi * 4 + r;
        op[(size_t)row * DD + dt * 16 + li] = o[rs][dt][r];
      }
  }
}

extern "C" void kernel_launch(void* const* d_in, const int* in_sizes, int n_in,
                              void* d_out, int out_size, void* d_ws, size_t ws_size,
                              hipStream_t stream) {
  (void)in_sizes; (void)n_in; (void)out_size; (void)d_ws; (void)ws_size;
  const float* Q = (const float*)d_in[0];
  const float* K = (const float*)d_in[1];
  const float* V = (const float*)d_in[2];
  const int*   M = (const int*)d_in[3];
  float* O = (float*)d_out;
  wattn<<<dim3(512), dim3(256), 0, stream>>>(Q, K, V, M, O);
}